// Round 18
// baseline (248.231 us; speedup 1.0000x reference)
//
#include <hip/hip_runtime.h>

// InterpretableMultiHeadAttention: B=8,S=1024,H=1024,NH=16,D=64,V=1024
// out = (mean_n softmax(causal(qh_n kh_n^T / 8))) @ (v Wv + bv)
// Round 18: proj_gemm -> counted-vmcnt TRIPLE-buffer pipeline (T3/T4):
// loads 2 K-steps ahead, s_waitcnt vmcnt(4) + raw s_barrier per step (never
// drain to 0 in-loop). Everything else identical to the proven r17 config.

#define NHEAD 16
#define BATCH 8
#define SEQ   1024
#define HID   1024
#define DHEAD 64

typedef _Float16 f16;
typedef _Float16 f16x4 __attribute__((ext_vector_type(4)));
typedef _Float16 f16x8 __attribute__((ext_vector_type(8)));
typedef float    f32x4 __attribute__((ext_vector_type(4)));

__device__ __forceinline__ f32x4 mfma16(f16x8 a, f16x8 b, f32x4 c) {
  return __builtin_amdgcn_mfma_f32_16x16x32_f16(a, b, c, 0, 0, 0);
}

__device__ __forceinline__ void gload16(const f16* g, f16* l) {
  __builtin_amdgcn_global_load_lds(
      (const __attribute__((address_space(1))) void*)g,
      (__attribute__((address_space(3))) void*)l, 16, 0, 0);
}

// GEMM staging (verified conflict-free). step = blockDim.x.
__device__ __forceinline__ void stage_swz(const f16* __restrict__ g, int ldg,
                                          f16* lds, int nch, int tid,
                                          int step = 256) {
  for (int idx = tid; idx < nch; idx += step) {
    int row = idx >> 3, c16 = idx & 7;
    int sc = c16 ^ (row & 7);
    gload16(g + (size_t)row * ldg + sc * 8, lds + (size_t)(idx & ~63) * 8);
  }
}

__device__ __forceinline__ f16x8 lds_frag(const f16* lds, int row, int c16) {
  int sc = c16 ^ (row & 7);
  return *(const f16x8*)&lds[row * 64 + sc * 8];
}

// ---------------- conversions ----------------

__global__ __launch_bounds__(256) void conv3(
    const float* __restrict__ q, const float* __restrict__ k,
    const float* __restrict__ v, f16* __restrict__ dq, f16* __restrict__ dk,
    f16* __restrict__ dv) {
  const float* src = blockIdx.z == 0 ? q : blockIdx.z == 1 ? k : v;
  f16* dst = blockIdx.z == 0 ? dq : blockIdx.z == 1 ? dk : dv;
  int i = (blockIdx.x * 256 + threadIdx.x) * 4;
  float4 f = *(const float4*)(src + i);
  f16x4 o = { (f16)f.x, (f16)f.y, (f16)f.z, (f16)f.w };
  *(f16x4*)(dst + i) = o;
}

__global__ __launch_bounds__(256) void tconv2(
    const float* __restrict__ s0, const float* __restrict__ s1,
    f16* __restrict__ d0, f16* __restrict__ d1, int R, int C, int half) {
  int z = blockIdx.z;
  const float* src; f16* dst;
  if (z < half) { src = s0 + (size_t)z * R * C; dst = d0 + (size_t)z * R * C; }
  else { src = s1 + (size_t)(z - half) * R * C; dst = d1 + (size_t)(z - half) * R * C; }
  const int c0 = blockIdx.x * 64, r0 = blockIdx.y * 64;
  __shared__ f16 t[64][72];
  const int tid = threadIdx.x;
#pragma unroll
  for (int i = 0; i < 4; i++) {
    int chunk = tid + i * 256;
    int row = chunk >> 4, c4 = chunk & 15;
    float4 f = *(const float4*)&src[(size_t)(r0 + row) * C + c0 + c4 * 4];
    f16x4 h = { (f16)f.x, (f16)f.y, (f16)f.z, (f16)f.w };
    *(f16x4*)&t[row][c4 * 4] = h;
  }
  __syncthreads();
  const int cc = tid >> 2, q = tid & 3;
  f16 tmp[16];
#pragma unroll
  for (int j = 0; j < 16; j++) tmp[j] = t[q * 16 + j][cc];
  *(f16x8*)&dst[(size_t)(c0 + cc) * R + r0 + q * 16] = *(f16x8*)&tmp[0];
  *(f16x8*)&dst[(size_t)(c0 + cc) * R + r0 + q * 16 + 8] = *(f16x8*)&tmp[8];
}

// ---------------- shared GEMM core: 128x128 tile, BK=64, 4 waves ----------------

__device__ __forceinline__ void gemm_core(
    const f16* __restrict__ A, const f16* __restrict__ Bt, int K, int Kend,
    int row0, int col0, f16* la, f16* lb, int tid, f32x4 (&acc)[4][4]) {
  const int lane = tid & 63;
  const int wr = (tid >> 6) >> 1, wc = (tid >> 6) & 1;
  for (int k0 = 0; k0 < Kend; k0 += 64) {
    __syncthreads();
    stage_swz(A + (size_t)row0 * K + k0, K, la, 1024, tid);
    stage_swz(Bt + (size_t)col0 * K + k0, K, lb, 1024, tid);
    __syncthreads();
#pragma unroll
    for (int ks = 0; ks < 2; ks++) {
      f16x8 af[4], bfr[4];
#pragma unroll
      for (int mi = 0; mi < 4; mi++)
        af[mi] = lds_frag(la, wr * 64 + mi * 16 + (lane & 15), ks * 4 + (lane >> 4));
#pragma unroll
      for (int ni = 0; ni < 4; ni++)
        bfr[ni] = lds_frag(lb, wc * 64 + ni * 16 + (lane & 15), ks * 4 + (lane >> 4));
#pragma unroll
      for (int mi = 0; mi < 4; mi++)
#pragma unroll
        for (int ni = 0; ni < 4; ni++)
          acc[mi][ni] = mfma16(af[mi], bfr[ni], acc[mi][ni]);
    }
  }
}

// ---------------- projection GEMM: triple-buffered counted-vmcnt pipeline ---
// 512 thr / 8 waves (2x4, wave tile 64x32). K=1024 -> 16 steps. Loads run two
// steps ahead (8 in flight/thread); per step: vmcnt(4) retires only step-t's
// loads, raw s_barrier publishes, STAGE(t+2) refills the buffer freed by t-1.

__global__ __launch_bounds__(512, 1) void proj_gemm(
    const f16* __restrict__ A0, const f16* __restrict__ A1,
    const f16* __restrict__ Bt0, const f16* __restrict__ Bt1,
    const float* __restrict__ bias0, const float* __restrict__ bias1,
    f16* __restrict__ C0, f16* __restrict__ C1) {
  const int which = blockIdx.z;
  const f16* A = which ? A1 : A0;
  const f16* Bt = which ? Bt1 : Bt0;
  const float* bias = which ? bias1 : bias0;
  f16* C = which ? C1 : C0;

  __shared__ alignas(16) f16 la[3][128 * 64];
  __shared__ alignas(16) f16 lb[3][128 * 64];

  const int tid = threadIdx.x, lane = tid & 63;
  const int wave = tid >> 6;
  const int wr = wave >> 2, wc = wave & 3;   // 2x4 wave grid, tile 64x32
  const int lr = lane & 15, qg = lane >> 4;
  const int row0 = blockIdx.x * 128, col0 = blockIdx.y * 128;
  const f16* Arow = A + (size_t)row0 * HID;
  const f16* Brow = Bt + (size_t)col0 * HID;

  f32x4 acc[4][2];
#pragma unroll
  for (int i = 0; i < 4; i++)
#pragma unroll
    for (int j = 0; j < 2; j++) acc[i][j] = (f32x4){0.f, 0.f, 0.f, 0.f};

  // prologue: stage steps 0 and 1 (4 loads/thread each)
  stage_swz(Arow, HID, la[0], 1024, tid, 512);
  stage_swz(Brow, HID, lb[0], 1024, tid, 512);
  stage_swz(Arow + 64, HID, la[1], 1024, tid, 512);
  stage_swz(Brow + 64, HID, lb[1], 1024, tid, 512);

  int cur = 0, nxt2 = 2;   // buf index of step t, and of step t+2
  for (int t = 0; t < 16; ++t) {
    // retire step-t's 4 loads; keep step t+1's 4 in flight (never drain to 0)
    if (t < 15) asm volatile("s_waitcnt vmcnt(4)" ::: "memory");
    else        asm volatile("s_waitcnt vmcnt(0)" ::: "memory");
    __builtin_amdgcn_s_barrier();          // publish LDS writes to all waves
    __builtin_amdgcn_sched_barrier(0);     // pin: nothing hoists above here

    if (t + 2 < 16) {  // refill buffer freed by step t-1 (all waves past it)
      stage_swz(Arow + (t + 2) * 64, HID, la[nxt2], 1024, tid, 512);
      stage_swz(Brow + (t + 2) * 64, HID, lb[nxt2], 1024, tid, 512);
    }

#pragma unroll
    for (int ks = 0; ks < 2; ks++) {
      f16x8 af[4], bfr[2];
#pragma unroll
      for (int mi = 0; mi < 4; mi++)
        af[mi] = lds_frag(la[cur], wr * 64 + mi * 16 + lr, ks * 4 + qg);
#pragma unroll
      for (int ni = 0; ni < 2; ni++)
        bfr[ni] = lds_frag(lb[cur], wc * 32 + ni * 16 + lr, ks * 4 + qg);
#pragma unroll
      for (int mi = 0; mi < 4; mi++)
#pragma unroll
        for (int ni = 0; ni < 2; ni++)
          acc[mi][ni] = mfma16(af[mi], bfr[ni], acc[mi][ni]);
    }
    cur = cur == 2 ? 0 : cur + 1;
    nxt2 = nxt2 == 2 ? 0 : nxt2 + 1;
  }

#pragma unroll
  for (int mi = 0; mi < 4; mi++)
#pragma unroll
    for (int ni = 0; ni < 2; ni++)
#pragma unroll
      for (int r = 0; r < 4; r++) {
        int m = row0 + wr * 64 + mi * 16 + qg * 4 + r;
        int j = col0 + wc * 32 + ni * 16 + lr;
        float val = acc[mi][ni][r] + bias[j];
        int bb = m >> 10, s = m & 1023, hn = j >> 6, d = j & 63;
        C[(((size_t)hn * BATCH + bb) * SEQ + s) * DHEAD + d] = (f16)val;
      }
}

// ---------------- vv GEMM: vvT[b][v][t] = WvT x v^T + bv[row] ----------------

__global__ __launch_bounds__(256) void vv_gemm(
    const f16* __restrict__ A, const f16* __restrict__ Bt,
    const float* __restrict__ bias, f16* __restrict__ C) {
  __shared__ alignas(16) f16 la[128 * 64];
  __shared__ alignas(16) f16 lb[128 * 64];
  const int tid = threadIdx.x, lane = tid & 63;
  const int wr = (tid >> 6) >> 1, wc = (tid >> 6) & 1;
  const int row0 = blockIdx.x * 128, col0 = blockIdx.y * 128;
  f32x4 acc[4][4];
#pragma unroll
  for (int i = 0; i < 4; i++)
#pragma unroll
    for (int j = 0; j < 4; j++) acc[i][j] = (f32x4){0.f, 0.f, 0.f, 0.f};
  gemm_core(A, Bt, HID, HID, row0, col0, la, lb, tid, acc);
#pragma unroll
  for (int mi = 0; mi < 4; mi++)
#pragma unroll
    for (int ni = 0; ni < 4; ni++)
#pragma unroll
      for (int r = 0; r < 4; r++) {
        int m = row0 + wr * 64 + mi * 16 + ((lane >> 4) << 2) + r;
        int j = col0 + wc * 64 + ni * 16 + (lane & 15);
        float val = acc[mi][ni][r] + bias[m];
        int bb = j >> 10, t = j & 1023;
        C[((size_t)bb * SEQ + m) * SEQ + t] = (f16)val;
      }
}

// ---------------- attention pass 1: row sums, 64 rows/wave, K-split ----------
// (r9 proven version: LPT dispatch, K read once per block, LDS combine)

__global__ __launch_bounds__(256) void attn_stats(
    const f16* __restrict__ QH, const f16* __restrict__ KH,
    float* __restrict__ madj_ws) {
  const int flat = blockIdx.x;
  const int sb = 15 - (flat >> 7);
  const int nb = flat & 127;
  const int n = nb >> 3, b = nb & 7;
  const int s0 = sb * 64;
  const f16* qh = QH + ((size_t)n * BATCH + b) * SEQ * DHEAD;
  const f16* kh = KH + ((size_t)n * BATCH + b) * SEQ * DHEAD;

  const int tid = threadIdx.x, lane = tid & 63, wave = tid >> 6;
  const int lr = lane & 15;
  const int qg = lane >> 4;
  const int ch = qg << 3;

  f16x8 aq[4][2];
#pragma unroll
  for (int fi = 0; fi < 4; fi++) {
    const f16* qp = qh + (size_t)(s0 + fi * 16 + lr) * 64 + ch;
    aq[fi][0] = *(const f16x8*)qp;
    aq[fi][1] = *(const f16x8*)(qp + 32);
  }

  const float sl2e = 0.125f * 1.44269504088896f;
  float l_p[16];
#pragma unroll
  for (int i = 0; i < 16; i++) l_p[i] = 0.f;

  const int nt = (sb + 1) * 4;
  const int dstart = sb * 4;
  const int njw = (nt - wave + 3) >> 2;
  const f16* kp = kh + (size_t)lr * 64 + ch;

  f16x8 kA0, kA1, kB0, kB1;

#define LDK(jj, X0, X1) { const f16* p_ = kp + (size_t)(jj) * 1024; \
    X0 = *(const f16x8*)p_; X1 = *(const f16x8*)(p_ + 32); }

#define COMP(jj, X0, X1) { \
    f32x4 c_[4]; \
    _Pragma("unroll") for (int fi = 0; fi < 4; fi++) { \
      f32x4 cc = (f32x4){0.f, 0.f, 0.f, 0.f}; \
      cc = mfma16(aq[fi][0], X0, cc); cc = mfma16(aq[fi][1], X1, cc); \
      c_[fi] = cc; } \
    if ((jj) < dstart) { \
      _Pragma("unroll") for (int fi = 0; fi < 4; fi++) \
        _Pragma("unroll") for (int r = 0; r < 4; r++) \
          l_p[fi * 4 + r] += exp2f(c_[fi][r] * sl2e); \
    } else { \
      int tg_ = (jj) * 16 + lr; \
      _Pragma("unroll") for (int fi = 0; fi < 4; fi++) \
        _Pragma("unroll") for (int r = 0; r < 4; r++) { \
          int sg_ = s0 + fi * 16 + qg * 4 + r; \
          l_p[fi * 4 + r] += (tg_ <= sg_) ? exp2f(c_[fi][r] * sl2e) : 0.f; } } }

  LDK(wave, kA0, kA1);
  int idx = 0;
  for (; idx + 2 <= njw; idx += 2) {
    LDK(wave + (idx + 1) * 4, kB0, kB1);
    COMP(wave + idx * 4, kA0, kA1);
    if (idx + 2 < njw) LDK(wave + (idx + 2) * 4, kA0, kA1);
    COMP(wave + (idx + 1) * 4, kB0, kB1);
  }
  if (idx < njw) COMP(wave + idx * 4, kA0, kA1);
#undef LDK
#undef COMP

  __shared__ float lds_l[4][64];
#pragma unroll
  for (int i = 0; i < 16; i++) {
    float l = l_p[i];
    l += __shfl_xor(l, 1); l += __shfl_xor(l, 2);
    l += __shfl_xor(l, 4); l += __shfl_xor(l, 8);
    if (lr == 0) lds_l[wave][(i >> 2) * 16 + qg * 4 + (i & 3)] = l;
  }
  __syncthreads();
  if (tid < 64) {
    float l = lds_l[0][tid] + lds_l[1][tid] + lds_l[2][tid] + lds_l[3][tid];
    madj_ws[((size_t)n * BATCH + b) * SEQ + s0 + tid] = -__log2f(l) - 4.0f;
  }
}

// ---------------- pbar as GEMM: 512 thr / 8 waves, dbuf prefetch ------------
// flat grid 576 XCD-affine (2 (b,g) pairs per XCD). Wave grid 2x4, wave tile
// 64x32, acc[4][2]. Head h+1 staged into other buffer before head h's
// MFMA+exp2; ONE barrier per head.

__global__ __launch_bounds__(512, 4) void pbar_gemm(
    const f16* __restrict__ QH, const f16* __restrict__ KH,
    const float* __restrict__ madj_ws, f16* __restrict__ pp) {
  const int flat = blockIdx.x;
  const int wg = (flat & 7) * 72 + (flat >> 3);  // XCD-affine, bijective (576=8*72)
  const int y = wg / 36;                         // b*2+g : 2 pairs per XCD chunk
  int rb = 0, cb = 0;
  {
    int t = wg % 36;
#pragma unroll
    for (int r = 0; r < 8; ++r) {
      if (t <= r) { rb = r; cb = t; break; }
      t -= r + 1;
    }
  }
  const int r0 = rb * 128, c0 = cb * 128;
  const int b = y >> 1, g = y & 1;
  const int n0 = g * 8;
  const bool diag = (rb == cb);

  __shared__ alignas(16) f16 la[2][128 * 64];
  __shared__ alignas(16) f16 lb[2][128 * 64];

  const int tid = threadIdx.x, lane = tid & 63;
  const int wave = tid >> 6;
  const int wr = wave >> 2, wc = wave & 3;       // 2x4 wave grid
  const int lr = lane & 15, qg = lane >> 4;
  const float sl2e = 0.125f * 1.44269504088896f;
  const size_t HS = (size_t)BATCH * SEQ * DHEAD;
  const f16* qbase = QH + ((size_t)n0 * BATCH + b) * SEQ * DHEAD + (size_t)r0 * 64;
  const f16* kbase = KH + ((size_t)n0 * BATCH + b) * SEQ * DHEAD + (size_t)c0 * 64;
  const float* mbase = madj_ws + ((size_t)n0 * BATCH + b) * SEQ + r0 +
                       wr * 64 + qg * 4;

  f32x4 pacc[4][2];
#pragma unroll
  for (int i = 0; i < 4; i++)
#pragma unroll
    for (int j = 0; j < 2; j++) pacc[i][j] = (f32x4){0.f, 0.f, 0.f, 0.f};

  stage_swz(qbase, 64, la[0], 1024, tid, 512);
  stage_swz(kbase, 64, lb[0], 1024, tid, 512);
  __syncthreads();

  for (int h = 0; h < 8; ++h) {
    const int cur = h & 1;
    if (h + 1 < 8) {  // prefetch next head into the other buffer
      stage_swz(qbase + (size_t)(h + 1) * HS, 64, la[cur ^ 1], 1024, tid, 512);
      stage_swz(kbase + (size_t)(h + 1) * HS, 64, lb[cur ^ 1], 1024, tid, 512);
    }
    const float* mb = mbase + (size_t)h * BATCH * SEQ;
    float4 m4[4];
#pragma unroll
    for (int mi = 0; mi < 4; mi++) m4[mi] = *(const float4*)(mb + mi * 16);

    f32x4 acc[4][2];
#pragma unroll
    for (int i = 0; i < 4; i++)
#pragma unroll
      for (int j = 0; j < 2; j++) acc[i][j] = (f32x4){0.f, 0.f, 0.f, 0.f};

#pragma unroll
    for (int ks = 0; ks < 2; ks++) {
      f16x8 af[4], bfr[2];
#pragma unroll
      for (int mi = 0; mi < 4; mi++)
        af[mi] = lds_frag(la[cur], wr * 64 + mi * 16 + lr, ks * 4 + qg);
#pragma unroll
      for (int ni = 0; ni < 2; ni++)
        bfr[ni] = lds_frag(lb[cur], wc * 32 + ni * 16 + lr, ks * 4 + qg);
#pragma unroll
      for (int mi = 0; mi < 4; mi++)
#pragma unroll
        for (int ni = 0; ni < 2; ni++)
          acc[mi][ni] = mfma16(af[mi], bfr[ni], acc[mi][ni]);
    }

#pragma unroll
    for (int mi = 0; mi < 4; mi++) {
      float ma[4] = {m4[mi].x, m4[mi].y, m4[mi].z, m4[mi].w};
#pragma unroll
      for (int ni = 0; ni < 2; ni++) {
        int tg = c0 + wc * 32 + ni * 16 + lr;
#pragma unroll
        for (int r = 0; r < 4; r++) {
          float p = exp2f(fmaf(acc[mi][ni][r], sl2e, ma[r]));
          if (diag) {
            int sg = r0 + wr * 64 + mi * 16 + qg * 4 + r;
            p = (tg <= sg) ? p : 0.f;
          }
          pacc[mi][ni][r] += p;
        }
      }
    }
    __syncthreads();  // drains h+1 prefetch; protects buffer reuse at h+2
  }

  f16* out = pp + ((size_t)g * BATCH + b) * SEQ * SEQ;
#pragma unroll
  for (int mi = 0; mi < 4; mi++)
#pragma unroll
    for (int ni = 0; ni < 2; ni++)
#pragma unroll
      for (int r = 0; r < 4; r++) {
        int m = r0 + wr * 64 + mi * 16 + qg * 4 + r;
        int j = c0 + wc * 32 + ni * 16 + lr;
        out[(size_t)m * SEQ + j] = (f16)pacc[mi][ni][r];
      }
}

// ---------------- PV: out[b] = (pp0[b] + pp1[b]) @ vv[b], causal K-limit ----

__global__ __launch_bounds__(256) void pv_gemm(
    const f16* __restrict__ pp, const f16* __restrict__ vvT,
    float* __restrict__ out) {
  const int b = blockIdx.z;
  const size_t GS = (size_t)BATCH * SEQ * SEQ;
  const f16* A0 = pp + (size_t)b * SEQ * SEQ;
  const f16* A1 = pp + GS + (size_t)b * SEQ * SEQ;
  const f16* Bt = vvT + (size_t)b * SEQ * SEQ;
  __shared__ alignas(16) f16 la0[128 * 64];
  __shared__ alignas(16) f16 la1[128 * 64];
  __shared__ alignas(16) f16 lb[128 * 64];
  const int tid = threadIdx.x, lane = tid & 63;
  const int wr = (tid >> 6) >> 1, wc = (tid >> 6) & 1;
  const int row0 = blockIdx.x * 128, col0 = blockIdx.y * 128;
  const int Kend = (row0 + 128 < SEQ) ? row0 + 128 : SEQ;

  f32x4 acc[4][4];
#pragma unroll
  for (int i = 0; i < 4; i++)
#pragma unroll
    for (int j = 0; j < 4; j++) acc[i][j] = (f32x4){0.f, 0.f, 0.f, 0.f};

  for (int k0 = 0; k0 < Kend; k0 += 64) {
    __syncthreads();
    stage_swz(A0 + (size_t)row0 * SEQ + k0, SEQ, la0, 1024, tid);
    stage_swz(A1 + (size_t)row0 * SEQ + k0, SEQ, la1, 1024, tid);
    stage_swz(Bt + (size_t)col0 * SEQ + k0, SEQ, lb, 1024, tid);
    __syncthreads();
#pragma unroll
    for (int ks = 0; ks < 2; ks++) {
      f16x8 a0[4], a1[4], bfr[4];
#pragma unroll
      for (int mi = 0; mi < 4; mi++) {
        a0[mi] = lds_frag(la0, wr * 64 + mi * 16 + (lane & 15), ks * 4 + (lane >> 4));
        a1[mi] = lds_frag(la1, wr * 64 + mi * 16 + (lane & 15), ks * 4 + (lane >> 4));
      }
#pragma unroll
      for (int ni = 0; ni < 4; ni++)
        bfr[ni] = lds_frag(lb, wc * 64 + ni * 16 + (lane & 15), ks * 4 + (lane >> 4));
#pragma unroll
      for (int mi = 0; mi < 4; mi++)
#pragma unroll
        for (int ni = 0; ni < 4; ni++) {
          acc[mi][ni] = mfma16(a0[mi], bfr[ni], acc[mi][ni]);
          acc[mi][ni] = mfma16(a1[mi], bfr[ni], acc[mi][ni]);
        }
    }
  }

#pragma unroll
  for (int mi = 0; mi < 4; mi++)
#pragma unroll
    for (int ni = 0; ni < 4; ni++)
#pragma unroll
      for (int r = 0; r < 4; r++) {
        int m = row0 + wr * 64 + mi * 16 + ((lane >> 4) << 2) + r;
        int j = col0 + wc * 64 + ni * 16 + (lane & 15);
        out[(size_t)b * SEQ * SEQ + (size_t)m * SEQ + j] = acc[mi][ni][r];
      }
}

// ---------------- launcher ----------------

extern "C" void kernel_launch(void* const* d_in, const int* in_sizes, int n_in,
                              void* d_out, int out_size, void* d_ws, size_t ws_size,
                              hipStream_t stream) {
  (void)in_sizes; (void)n_in; (void)out_size; (void)ws_size;
  const float* q  = (const float*)d_in[0];
  const float* k  = (const float*)d_in[1];
  const float* v  = (const float*)d_in[2];
  const float* Wq = (const float*)d_in[3];
  const float* bq = (const float*)d_in[4];
  const float* Wk = (const float*)d_in[5];
  const float* bk = (const float*)d_in[6];
  const float* Wv = (const float*)d_in[7];
  const float* bv = (const float*)d_in[8];
  float* out = (float*)d_out;

  const size_t EL  = (size_t)BATCH * SEQ * HID;      // 8388608
  const size_t WEL = (size_t)NHEAD * HID * DHEAD;    // 1048576

  char* ws = (char*)d_ws;
  f16* qbf = (f16*)ws;  ws += EL * 2;
  f16* kbf = (f16*)ws;  ws += EL * 2;
  f16* vbf = (f16*)ws;  ws += EL * 2;
  f16* WqT = (f16*)ws;  ws += WEL * 2;
  f16* WkT = (f16*)ws;  ws += WEL * 2;
  f16* WvT = (f16*)ws;  ws += WEL * 2;
  f16* QHb = (f16*)ws;  ws += EL * 2;   // [n][b][s][d]
  f16* KHb = (f16*)ws;  ws += EL * 2;   // [n][b][t][d]
  f16* vvT = (f16*)ws;  ws += EL * 2;   // [b][v][t]
  float* madj_ws = (float*)ws; ws += (size_t)NHEAD * BATCH * SEQ * 4;
  // pp[2][b][s][t] f16 overlays qbf+kbf (dead after proj GEMMs)
  f16* pp = qbf;

  conv3<<<dim3(8192, 1, 3), 256, 0, stream>>>(q, k, v, qbf, kbf, vbf);
  tconv2<<<dim3(1, 16, 32), 256, 0, stream>>>(Wq, Wk, WqT, WkT, 1024, 64, 16);
  tconv2<<<dim3(16, 16, 1), 256, 0, stream>>>(Wv, Wv, WvT, WvT, 1024, 1024, 1);

  proj_gemm<<<dim3(64, 8, 2), 512, 0, stream>>>(qbf, kbf, WqT, WkT, bq, bk,
                                                QHb, KHb);
  vv_gemm<<<dim3(8, 64, 1), 256, 0, stream>>>(WvT, vbf, bv, vvT);

  attn_stats<<<dim3(2048, 1, 1), 256, 0, stream>>>(QHb, KHb, madj_ws);
  pbar_gemm<<<dim3(576, 1, 1), 512, 0, stream>>>(QHb, KHb, madj_ws, pp);
  pv_gemm<<<dim3(8, 8, 8), 256, 0, stream>>>(pp, vvT, out);
}

// Round 19
// 225.090 us; speedup vs baseline: 1.1028x; 1.1028x over previous
//
#include <hip/hip_runtime.h>

// InterpretableMultiHeadAttention: B=8,S=1024,H=1024,NH=16,D=64,V=1024
// out = (mean_n softmax(causal(qh_n kh_n^T / 8))) @ (v Wv + bv)
// Round 19: restore the twice-measured best config (r14/r17, 225.8 us).
// proj/vv 256thr 2-phase, stats r9 256thr, pbar 512thr dbuf XCD-affine,
// pv dual-A. Structural pipelining attempts (r15/r16/r18) all regressed:
// 128-tile counted-vmcnt/8-phase is null at this grid shape (1 block/CU).

#define NHEAD 16
#define BATCH 8
#define SEQ   1024
#define HID   1024
#define DHEAD 64

typedef _Float16 f16;
typedef _Float16 f16x4 __attribute__((ext_vector_type(4)));
typedef _Float16 f16x8 __attribute__((ext_vector_type(8)));
typedef float    f32x4 __attribute__((ext_vector_type(4)));

__device__ __forceinline__ f32x4 mfma16(f16x8 a, f16x8 b, f32x4 c) {
  return __builtin_amdgcn_mfma_f32_16x16x32_f16(a, b, c, 0, 0, 0);
}

__device__ __forceinline__ void gload16(const f16* g, f16* l) {
  __builtin_amdgcn_global_load_lds(
      (const __attribute__((address_space(1))) void*)g,
      (__attribute__((address_space(3))) void*)l, 16, 0, 0);
}

// GEMM staging (verified conflict-free). step = blockDim.x.
__device__ __forceinline__ void stage_swz(const f16* __restrict__ g, int ldg,
                                          f16* lds, int nch, int tid,
                                          int step = 256) {
  for (int idx = tid; idx < nch; idx += step) {
    int row = idx >> 3, c16 = idx & 7;
    int sc = c16 ^ (row & 7);
    gload16(g + (size_t)row * ldg + sc * 8, lds + (size_t)(idx & ~63) * 8);
  }
}

__device__ __forceinline__ f16x8 lds_frag(const f16* lds, int row, int c16) {
  int sc = c16 ^ (row & 7);
  return *(const f16x8*)&lds[row * 64 + sc * 8];
}

// ---------------- conversions ----------------

__global__ __launch_bounds__(256) void conv3(
    const float* __restrict__ q, const float* __restrict__ k,
    const float* __restrict__ v, f16* __restrict__ dq, f16* __restrict__ dk,
    f16* __restrict__ dv) {
  const float* src = blockIdx.z == 0 ? q : blockIdx.z == 1 ? k : v;
  f16* dst = blockIdx.z == 0 ? dq : blockIdx.z == 1 ? dk : dv;
  int i = (blockIdx.x * 256 + threadIdx.x) * 4;
  float4 f = *(const float4*)(src + i);
  f16x4 o = { (f16)f.x, (f16)f.y, (f16)f.z, (f16)f.w };
  *(f16x4*)(dst + i) = o;
}

__global__ __launch_bounds__(256) void tconv2(
    const float* __restrict__ s0, const float* __restrict__ s1,
    f16* __restrict__ d0, f16* __restrict__ d1, int R, int C, int half) {
  int z = blockIdx.z;
  const float* src; f16* dst;
  if (z < half) { src = s0 + (size_t)z * R * C; dst = d0 + (size_t)z * R * C; }
  else { src = s1 + (size_t)(z - half) * R * C; dst = d1 + (size_t)(z - half) * R * C; }
  const int c0 = blockIdx.x * 64, r0 = blockIdx.y * 64;
  __shared__ f16 t[64][72];
  const int tid = threadIdx.x;
#pragma unroll
  for (int i = 0; i < 4; i++) {
    int chunk = tid + i * 256;
    int row = chunk >> 4, c4 = chunk & 15;
    float4 f = *(const float4*)&src[(size_t)(r0 + row) * C + c0 + c4 * 4];
    f16x4 h = { (f16)f.x, (f16)f.y, (f16)f.z, (f16)f.w };
    *(f16x4*)&t[row][c4 * 4] = h;
  }
  __syncthreads();
  const int cc = tid >> 2, q = tid & 3;
  f16 tmp[16];
#pragma unroll
  for (int j = 0; j < 16; j++) tmp[j] = t[q * 16 + j][cc];
  *(f16x8*)&dst[(size_t)(c0 + cc) * R + r0 + q * 16] = *(f16x8*)&tmp[0];
  *(f16x8*)&dst[(size_t)(c0 + cc) * R + r0 + q * 16 + 8] = *(f16x8*)&tmp[8];
}

// ---------------- shared GEMM core: 128x128 tile, BK=64, 4 waves ----------------

__device__ __forceinline__ void gemm_core(
    const f16* __restrict__ A, const f16* __restrict__ Bt, int K, int Kend,
    int row0, int col0, f16* la, f16* lb, int tid, f32x4 (&acc)[4][4]) {
  const int lane = tid & 63;
  const int wr = (tid >> 6) >> 1, wc = (tid >> 6) & 1;
  for (int k0 = 0; k0 < Kend; k0 += 64) {
    __syncthreads();
    stage_swz(A + (size_t)row0 * K + k0, K, la, 1024, tid);
    stage_swz(Bt + (size_t)col0 * K + k0, K, lb, 1024, tid);
    __syncthreads();
#pragma unroll
    for (int ks = 0; ks < 2; ks++) {
      f16x8 af[4], bfr[4];
#pragma unroll
      for (int mi = 0; mi < 4; mi++)
        af[mi] = lds_frag(la, wr * 64 + mi * 16 + (lane & 15), ks * 4 + (lane >> 4));
#pragma unroll
      for (int ni = 0; ni < 4; ni++)
        bfr[ni] = lds_frag(lb, wc * 64 + ni * 16 + (lane & 15), ks * 4 + (lane >> 4));
#pragma unroll
      for (int mi = 0; mi < 4; mi++)
#pragma unroll
        for (int ni = 0; ni < 4; ni++)
          acc[mi][ni] = mfma16(af[mi], bfr[ni], acc[mi][ni]);
    }
  }
}

// ---------------- projection GEMM (q & k batched via z) ----------------

__global__ __launch_bounds__(256) void proj_gemm(
    const f16* __restrict__ A0, const f16* __restrict__ A1,
    const f16* __restrict__ Bt0, const f16* __restrict__ Bt1,
    const float* __restrict__ bias0, const float* __restrict__ bias1,
    f16* __restrict__ C0, f16* __restrict__ C1) {
  const int which = blockIdx.z;
  const f16* A = which ? A1 : A0;
  const f16* Bt = which ? Bt1 : Bt0;
  const float* bias = which ? bias1 : bias0;
  f16* C = which ? C1 : C0;
  __shared__ alignas(16) f16 la[128 * 64];
  __shared__ alignas(16) f16 lb[128 * 64];
  const int tid = threadIdx.x, lane = tid & 63;
  const int wr = (tid >> 6) >> 1, wc = (tid >> 6) & 1;
  const int row0 = blockIdx.x * 128, col0 = blockIdx.y * 128;
  f32x4 acc[4][4];
#pragma unroll
  for (int i = 0; i < 4; i++)
#pragma unroll
    for (int j = 0; j < 4; j++) acc[i][j] = (f32x4){0.f, 0.f, 0.f, 0.f};
  gemm_core(A, Bt, HID, HID, row0, col0, la, lb, tid, acc);
#pragma unroll
  for (int mi = 0; mi < 4; mi++)
#pragma unroll
    for (int ni = 0; ni < 4; ni++)
#pragma unroll
      for (int r = 0; r < 4; r++) {
        int m = row0 + wr * 64 + mi * 16 + ((lane >> 4) << 2) + r;
        int j = col0 + wc * 64 + ni * 16 + (lane & 15);
        float val = acc[mi][ni][r] + bias[j];
        int bb = m >> 10, s = m & 1023, hn = j >> 6, d = j & 63;
        C[(((size_t)hn * BATCH + bb) * SEQ + s) * DHEAD + d] = (f16)val;
      }
}

// ---------------- vv GEMM: vvT[b][v][t] = WvT x v^T + bv[row] ----------------

__global__ __launch_bounds__(256) void vv_gemm(
    const f16* __restrict__ A, const f16* __restrict__ Bt,
    const float* __restrict__ bias, f16* __restrict__ C) {
  __shared__ alignas(16) f16 la[128 * 64];
  __shared__ alignas(16) f16 lb[128 * 64];
  const int tid = threadIdx.x, lane = tid & 63;
  const int wr = (tid >> 6) >> 1, wc = (tid >> 6) & 1;
  const int row0 = blockIdx.x * 128, col0 = blockIdx.y * 128;
  f32x4 acc[4][4];
#pragma unroll
  for (int i = 0; i < 4; i++)
#pragma unroll
    for (int j = 0; j < 4; j++) acc[i][j] = (f32x4){0.f, 0.f, 0.f, 0.f};
  gemm_core(A, Bt, HID, HID, row0, col0, la, lb, tid, acc);
#pragma unroll
  for (int mi = 0; mi < 4; mi++)
#pragma unroll
    for (int ni = 0; ni < 4; ni++)
#pragma unroll
      for (int r = 0; r < 4; r++) {
        int m = row0 + wr * 64 + mi * 16 + ((lane >> 4) << 2) + r;
        int j = col0 + wc * 64 + ni * 16 + (lane & 15);
        float val = acc[mi][ni][r] + bias[m];
        int bb = j >> 10, t = j & 1023;
        C[((size_t)bb * SEQ + m) * SEQ + t] = (f16)val;
      }
}

// ---------------- attention pass 1: row sums, 64 rows/wave, K-split ----------
// (r9 proven version: LPT dispatch, K read once per block, LDS combine)

__global__ __launch_bounds__(256) void attn_stats(
    const f16* __restrict__ QH, const f16* __restrict__ KH,
    float* __restrict__ madj_ws) {
  const int flat = blockIdx.x;
  const int sb = 15 - (flat >> 7);
  const int nb = flat & 127;
  const int n = nb >> 3, b = nb & 7;
  const int s0 = sb * 64;
  const f16* qh = QH + ((size_t)n * BATCH + b) * SEQ * DHEAD;
  const f16* kh = KH + ((size_t)n * BATCH + b) * SEQ * DHEAD;

  const int tid = threadIdx.x, lane = tid & 63, wave = tid >> 6;
  const int lr = lane & 15;
  const int qg = lane >> 4;
  const int ch = qg << 3;

  f16x8 aq[4][2];
#pragma unroll
  for (int fi = 0; fi < 4; fi++) {
    const f16* qp = qh + (size_t)(s0 + fi * 16 + lr) * 64 + ch;
    aq[fi][0] = *(const f16x8*)qp;
    aq[fi][1] = *(const f16x8*)(qp + 32);
  }

  const float sl2e = 0.125f * 1.44269504088896f;
  float l_p[16];
#pragma unroll
  for (int i = 0; i < 16; i++) l_p[i] = 0.f;

  const int nt = (sb + 1) * 4;
  const int dstart = sb * 4;
  const int njw = (nt - wave + 3) >> 2;
  const f16* kp = kh + (size_t)lr * 64 + ch;

  f16x8 kA0, kA1, kB0, kB1;

#define LDK(jj, X0, X1) { const f16* p_ = kp + (size_t)(jj) * 1024; \
    X0 = *(const f16x8*)p_; X1 = *(const f16x8*)(p_ + 32); }

#define COMP(jj, X0, X1) { \
    f32x4 c_[4]; \
    _Pragma("unroll") for (int fi = 0; fi < 4; fi++) { \
      f32x4 cc = (f32x4){0.f, 0.f, 0.f, 0.f}; \
      cc = mfma16(aq[fi][0], X0, cc); cc = mfma16(aq[fi][1], X1, cc); \
      c_[fi] = cc; } \
    if ((jj) < dstart) { \
      _Pragma("unroll") for (int fi = 0; fi < 4; fi++) \
        _Pragma("unroll") for (int r = 0; r < 4; r++) \
          l_p[fi * 4 + r] += exp2f(c_[fi][r] * sl2e); \
    } else { \
      int tg_ = (jj) * 16 + lr; \
      _Pragma("unroll") for (int fi = 0; fi < 4; fi++) \
        _Pragma("unroll") for (int r = 0; r < 4; r++) { \
          int sg_ = s0 + fi * 16 + qg * 4 + r; \
          l_p[fi * 4 + r] += (tg_ <= sg_) ? exp2f(c_[fi][r] * sl2e) : 0.f; } } }

  LDK(wave, kA0, kA1);
  int idx = 0;
  for (; idx + 2 <= njw; idx += 2) {
    LDK(wave + (idx + 1) * 4, kB0, kB1);
    COMP(wave + idx * 4, kA0, kA1);
    if (idx + 2 < njw) LDK(wave + (idx + 2) * 4, kA0, kA1);
    COMP(wave + (idx + 1) * 4, kB0, kB1);
  }
  if (idx < njw) COMP(wave + idx * 4, kA0, kA1);
#undef LDK
#undef COMP

  __shared__ float lds_l[4][64];
#pragma unroll
  for (int i = 0; i < 16; i++) {
    float l = l_p[i];
    l += __shfl_xor(l, 1); l += __shfl_xor(l, 2);
    l += __shfl_xor(l, 4); l += __shfl_xor(l, 8);
    if (lr == 0) lds_l[wave][(i >> 2) * 16 + qg * 4 + (i & 3)] = l;
  }
  __syncthreads();
  if (tid < 64) {
    float l = lds_l[0][tid] + lds_l[1][tid] + lds_l[2][tid] + lds_l[3][tid];
    madj_ws[((size_t)n * BATCH + b) * SEQ + s0 + tid] = -__log2f(l) - 4.0f;
  }
}

// ---------------- pbar as GEMM: 512 thr / 8 waves, dbuf prefetch ------------
// flat grid 576 XCD-affine (2 (b,g) pairs per XCD). Wave grid 2x4, wave tile
// 64x32, acc[4][2]. Head h+1 staged into other buffer before head h's
// MFMA+exp2; ONE barrier per head.

__global__ __launch_bounds__(512, 4) void pbar_gemm(
    const f16* __restrict__ QH, const f16* __restrict__ KH,
    const float* __restrict__ madj_ws, f16* __restrict__ pp) {
  const int flat = blockIdx.x;
  const int wg = (flat & 7) * 72 + (flat >> 3);  // XCD-affine, bijective (576=8*72)
  const int y = wg / 36;                         // b*2+g : 2 pairs per XCD chunk
  int rb = 0, cb = 0;
  {
    int t = wg % 36;
#pragma unroll
    for (int r = 0; r < 8; ++r) {
      if (t <= r) { rb = r; cb = t; break; }
      t -= r + 1;
    }
  }
  const int r0 = rb * 128, c0 = cb * 128;
  const int b = y >> 1, g = y & 1;
  const int n0 = g * 8;
  const bool diag = (rb == cb);

  __shared__ alignas(16) f16 la[2][128 * 64];
  __shared__ alignas(16) f16 lb[2][128 * 64];

  const int tid = threadIdx.x, lane = tid & 63;
  const int wave = tid >> 6;
  const int wr = wave >> 2, wc = wave & 3;       // 2x4 wave grid
  const int lr = lane & 15, qg = lane >> 4;
  const float sl2e = 0.125f * 1.44269504088896f;
  const size_t HS = (size_t)BATCH * SEQ * DHEAD;
  const f16* qbase = QH + ((size_t)n0 * BATCH + b) * SEQ * DHEAD + (size_t)r0 * 64;
  const f16* kbase = KH + ((size_t)n0 * BATCH + b) * SEQ * DHEAD + (size_t)c0 * 64;
  const float* mbase = madj_ws + ((size_t)n0 * BATCH + b) * SEQ + r0 +
                       wr * 64 + qg * 4;

  f32x4 pacc[4][2];
#pragma unroll
  for (int i = 0; i < 4; i++)
#pragma unroll
    for (int j = 0; j < 2; j++) pacc[i][j] = (f32x4){0.f, 0.f, 0.f, 0.f};

  stage_swz(qbase, 64, la[0], 1024, tid, 512);
  stage_swz(kbase, 64, lb[0], 1024, tid, 512);
  __syncthreads();

  for (int h = 0; h < 8; ++h) {
    const int cur = h & 1;
    if (h + 1 < 8) {  // prefetch next head into the other buffer
      stage_swz(qbase + (size_t)(h + 1) * HS, 64, la[cur ^ 1], 1024, tid, 512);
      stage_swz(kbase + (size_t)(h + 1) * HS, 64, lb[cur ^ 1], 1024, tid, 512);
    }
    const float* mb = mbase + (size_t)h * BATCH * SEQ;
    float4 m4[4];
#pragma unroll
    for (int mi = 0; mi < 4; mi++) m4[mi] = *(const float4*)(mb + mi * 16);

    f32x4 acc[4][2];
#pragma unroll
    for (int i = 0; i < 4; i++)
#pragma unroll
      for (int j = 0; j < 2; j++) acc[i][j] = (f32x4){0.f, 0.f, 0.f, 0.f};

#pragma unroll
    for (int ks = 0; ks < 2; ks++) {
      f16x8 af[4], bfr[2];
#pragma unroll
      for (int mi = 0; mi < 4; mi++)
        af[mi] = lds_frag(la[cur], wr * 64 + mi * 16 + lr, ks * 4 + qg);
#pragma unroll
      for (int ni = 0; ni < 2; ni++)
        bfr[ni] = lds_frag(lb[cur], wc * 32 + ni * 16 + lr, ks * 4 + qg);
#pragma unroll
      for (int mi = 0; mi < 4; mi++)
#pragma unroll
        for (int ni = 0; ni < 2; ni++)
          acc[mi][ni] = mfma16(af[mi], bfr[ni], acc[mi][ni]);
    }

#pragma unroll
    for (int mi = 0; mi < 4; mi++) {
      float ma[4] = {m4[mi].x, m4[mi].y, m4[mi].z, m4[mi].w};
#pragma unroll
      for (int ni = 0; ni < 2; ni++) {
        int tg = c0 + wc * 32 + ni * 16 + lr;
#pragma unroll
        for (int r = 0; r < 4; r++) {
          float p = exp2f(fmaf(acc[mi][ni][r], sl2e, ma[r]));
          if (diag) {
            int sg = r0 + wr * 64 + mi * 16 + qg * 4 + r;
            p = (tg <= sg) ? p : 0.f;
          }
          pacc[mi][ni][r] += p;
        }
      }
    }
    __syncthreads();  // drains h+1 prefetch; protects buffer reuse at h+2
  }

  f16* out = pp + ((size_t)g * BATCH + b) * SEQ * SEQ;
#pragma unroll
  for (int mi = 0; mi < 4; mi++)
#pragma unroll
    for (int ni = 0; ni < 2; ni++)
#pragma unroll
      for (int r = 0; r < 4; r++) {
        int m = r0 + wr * 64 + mi * 16 + qg * 4 + r;
        int j = c0 + wc * 32 + ni * 16 + lr;
        out[(size_t)m * SEQ + j] = (f16)pacc[mi][ni][r];
      }
}

// ---------------- PV: out[b] = (pp0[b] + pp1[b]) @ vv[b], causal K-limit ----

__global__ __launch_bounds__(256) void pv_gemm(
    const f16* __restrict__ pp, const f16* __restrict__ vvT,
    float* __restrict__ out) {
  const int b = blockIdx.z;
  const size_t GS = (size_t)BATCH * SEQ * SEQ;
  const f16* A0 = pp + (size_t)b * SEQ * SEQ;
  const f16* A1 = pp + GS + (size_t)b * SEQ * SEQ;
  const f16* Bt = vvT + (size_t)b * SEQ * SEQ;
  __shared__ alignas(16) f16 la0[128 * 64];
  __shared__ alignas(16) f16 la1[128 * 64];
  __shared__ alignas(16) f16 lb[128 * 64];
  const int tid = threadIdx.x, lane = tid & 63;
  const int wr = (tid >> 6) >> 1, wc = (tid >> 6) & 1;
  const int row0 = blockIdx.x * 128, col0 = blockIdx.y * 128;
  const int Kend = (row0 + 128 < SEQ) ? row0 + 128 : SEQ;

  f32x4 acc[4][4];
#pragma unroll
  for (int i = 0; i < 4; i++)
#pragma unroll
    for (int j = 0; j < 4; j++) acc[i][j] = (f32x4){0.f, 0.f, 0.f, 0.f};

  for (int k0 = 0; k0 < Kend; k0 += 64) {
    __syncthreads();
    stage_swz(A0 + (size_t)row0 * SEQ + k0, SEQ, la0, 1024, tid);
    stage_swz(A1 + (size_t)row0 * SEQ + k0, SEQ, la1, 1024, tid);
    stage_swz(Bt + (size_t)col0 * SEQ + k0, SEQ, lb, 1024, tid);
    __syncthreads();
#pragma unroll
    for (int ks = 0; ks < 2; ks++) {
      f16x8 a0[4], a1[4], bfr[4];
#pragma unroll
      for (int mi = 0; mi < 4; mi++) {
        a0[mi] = lds_frag(la0, wr * 64 + mi * 16 + (lane & 15), ks * 4 + (lane >> 4));
        a1[mi] = lds_frag(la1, wr * 64 + mi * 16 + (lane & 15), ks * 4 + (lane >> 4));
      }
#pragma unroll
      for (int ni = 0; ni < 4; ni++)
        bfr[ni] = lds_frag(lb, wc * 64 + ni * 16 + (lane & 15), ks * 4 + (lane >> 4));
#pragma unroll
      for (int mi = 0; mi < 4; mi++)
#pragma unroll
        for (int ni = 0; ni < 4; ni++) {
          acc[mi][ni] = mfma16(a0[mi], bfr[ni], acc[mi][ni]);
          acc[mi][ni] = mfma16(a1[mi], bfr[ni], acc[mi][ni]);
        }
    }
  }

#pragma unroll
  for (int mi = 0; mi < 4; mi++)
#pragma unroll
    for (int ni = 0; ni < 4; ni++)
#pragma unroll
      for (int r = 0; r < 4; r++) {
        int m = row0 + wr * 64 + mi * 16 + ((lane >> 4) << 2) + r;
        int j = col0 + wc * 64 + ni * 16 + (lane & 15);
        out[(size_t)b * SEQ * SEQ + (size_t)m * SEQ + j] = acc[mi][ni][r];
      }
}

// ---------------- launcher ----------------

extern "C" void kernel_launch(void* const* d_in, const int* in_sizes, int n_in,
                              void* d_out, int out_size, void* d_ws, size_t ws_size,
                              hipStream_t stream) {
  (void)in_sizes; (void)n_in; (void)out_size; (void)ws_size;
  const float* q  = (const float*)d_in[0];
  const float* k  = (const float*)d_in[1];
  const float* v  = (const float*)d_in[2];
  const float* Wq = (const float*)d_in[3];
  const float* bq = (const float*)d_in[4];
  const float* Wk = (const float*)d_in[5];
  const float* bk = (const float*)d_in[6];
  const float* Wv = (const float*)d_in[7];
  const float* bv = (const float*)d_in[8];
  float* out = (float*)d_out;

  const size_t EL  = (size_t)BATCH * SEQ * HID;      // 8388608
  const size_t WEL = (size_t)NHEAD * HID * DHEAD;    // 1048576

  char* ws = (char*)d_ws;
  f16* qbf = (f16*)ws;  ws += EL * 2;
  f16* kbf = (f16*)ws;  ws += EL * 2;
  f16* vbf = (f16*)ws;  ws += EL * 2;
  f16* WqT = (f16*)ws;  ws += WEL * 2;
  f16* WkT = (f16*)ws;  ws += WEL * 2;
  f16* WvT = (f16*)ws;  ws += WEL * 2;
  f16* QHb = (f16*)ws;  ws += EL * 2;   // [n][b][s][d]
  f16* KHb = (f16*)ws;  ws += EL * 2;   // [n][b][t][d]
  f16* vvT = (f16*)ws;  ws += EL * 2;   // [b][v][t]
  float* madj_ws = (float*)ws; ws += (size_t)NHEAD * BATCH * SEQ * 4;
  // pp[2][b][s][t] f16 overlays qbf+kbf (dead after proj GEMMs)
  f16* pp = qbf;

  conv3<<<dim3(8192, 1, 3), 256, 0, stream>>>(q, k, v, qbf, kbf, vbf);
  tconv2<<<dim3(1, 16, 32), 256, 0, stream>>>(Wq, Wk, WqT, WkT, 1024, 64, 16);
  tconv2<<<dim3(16, 16, 1), 256, 0, stream>>>(Wv, Wv, WvT, WvT, 1024, 1024, 1);

  proj_gemm<<<dim3(64, 8, 2), 256, 0, stream>>>(qbf, kbf, WqT, WkT, bq, bk,
                                                QHb, KHb);
  vv_gemm<<<dim3(8, 64, 1), 256, 0, stream>>>(WvT, vbf, bv, vvT);

  attn_stats<<<dim3(2048, 1, 1), 256, 0, stream>>>(QHb, KHb, madj_ws);
  pbar_gemm<<<dim3(576, 1, 1), 512, 0, stream>>>(QHb, KHb, madj_ws, pp);
  pv_gemm<<<dim3(8, 8, 8), 256, 0, stream>>>(pp, vvT, out);
}